// Round 1
// baseline (632.270 us; speedup 1.0000x reference)
//
#include <hip/hip_runtime.h>

// Problem constants
#define BQ 4
#define NMAX 512
#define VD 128          // MESH_DIM (K)
#define NCLS 64         // C
#define JD 512          // J = MAX_N
#define NCLUT 5
#define BANK 4096
#define NB (NCLUT*BANK)     // 20480
#define CJ (NCLS*JD)        // 32768
#define SIMW (CJ + NB)      // 53248 similarity row width
#define MROWS (BQ*NMAX)     // 2048

// Output offsets (floats)
#define OUT0_OFF 0ull
#define OUT0_SZ  ((size_t)BQ*NMAX*SIMW)            // 109051904
#define OUT1_OFF OUT0_SZ
#define OUT1_SZ  ((size_t)BQ*NCLUT*CJ)             // 655360
#define OUT2_OFF (OUT1_OFF + OUT1_SZ)
#define OUT2_SZ  ((size_t)NCLS*VD*JD)              // 4194304
#define OUT3_OFF (OUT2_OFF + OUT2_SZ)
#define OUT3_SZ  ((size_t)VD*NB)                   // 2621440

typedef short bf16x8 __attribute__((ext_vector_type(8)));
typedef float f32x4 __attribute__((ext_vector_type(4)));

__device__ inline unsigned short f2bf(float f) {
    union { float f; unsigned int u; } x; x.f = f;
    unsigned int r = x.u + 0x7fffu + ((x.u >> 16) & 1u);   // RNE, finite inputs
    return (unsigned short)(r >> 16);
}

// ---- Prep A: features[:, :512, :] -> bf16 [2048][128] ----
__global__ void prep_a(const float* __restrict__ feat, unsigned short* __restrict__ Abf) {
    int idx = blockIdx.x * 256 + threadIdx.x;      // 0..262143
    int row = idx >> 7, v = idx & 127;
    int b = row >> 9, i = row & 511;
    Abf[idx] = f2bf(feat[(size_t)(b*517 + i)*128 + v]);
}

// ---- Prep BT: BT[n][k] bf16, n<32768 from memory[c,k,j], else clutter[k][n-32768] ----
__global__ void prep_bt(const float* __restrict__ mem, const float* __restrict__ clut,
                        unsigned short* __restrict__ BT) {
    __shared__ float tile[128*65];                 // [k][n_l], pad 65 -> 2-way max
    int t = threadIdx.x;
    int n0 = blockIdx.x * 64;
    int n_l = t & 63;
    int n = n0 + n_l;
    #pragma unroll
    for (int p = 0; p < 32; ++p) {
        int k = p*4 + (t >> 6);
        float v;
        if (n < CJ) {
            int c = n >> 9, j = n & 511;
            v = mem[c*65536 + k*512 + j];
        } else {
            v = clut[k*NB + (n - CJ)];
        }
        tile[k*65 + n_l] = v;
    }
    __syncthreads();
    int n2 = n0 + (t >> 2);
    int kq = t & 3;                                // k block of 32
    #pragma unroll
    for (int i = 0; i < 4; ++i) {
        union { unsigned short s[8]; float4 v; } u;
        #pragma unroll
        for (int j = 0; j < 8; ++j) {
            int k = kq*32 + i*8 + j;
            u.s[j] = f2bf(tile[k*65 + (t >> 2)]);
        }
        *(float4*)&BT[(size_t)n2*128 + kq*32 + i*8] = u.v;
    }
}

// ---- Main GEMM: out0[m][n] = sum_k A[m][k]*BT[n][k], 128x128 tile, MFMA bf16 ----
__global__ __launch_bounds__(256) void gemm_sim(const unsigned short* __restrict__ A,
                                                const unsigned short* __restrict__ BT,
                                                float* __restrict__ out0) {
    __shared__ unsigned short As[128*128];   // 32 KB, XOR-swizzled 16B chunks
    __shared__ unsigned short Bs[128*128];   // 32 KB
    int t = threadIdx.x;
    int n0 = blockIdx.x * 128;
    int m0 = blockIdx.y * 128;

    // stage: 2048 16B-chunks per matrix, 8 per thread, swizzle chunk id by row&15
    #pragma unroll
    for (int it = 0; it < 8; ++it) {
        int idx = it*256 + t;                 // chunk 0..2047
        int row = idx >> 4;
        int c = idx & 15;
        int sw = (c ^ (row & 15)) * 8;
        float4 va = *(const float4*)&A [(size_t)(m0+row)*128 + c*8];
        float4 vb = *(const float4*)&BT[(size_t)(n0+row)*128 + c*8];
        *(float4*)&As[row*128 + sw] = va;
        *(float4*)&Bs[row*128 + sw] = vb;
    }
    __syncthreads();

    int lane = t & 63, wave = t >> 6;
    int wm = (wave & 1) * 64, wn = (wave >> 1) * 64;
    int l16 = lane & 15, quad = lane >> 4;

    f32x4 acc[4][4];
    #pragma unroll
    for (int i = 0; i < 4; ++i)
        #pragma unroll
        for (int j = 0; j < 4; ++j) acc[i][j] = (f32x4){0.f,0.f,0.f,0.f};

    #pragma unroll
    for (int ks = 0; ks < 4; ++ks) {
        int chunk = ks*4 + quad;              // 16B chunk index in k
        int sw = (chunk ^ l16) * 8;
        bf16x8 a[4], b[4];
        #pragma unroll
        for (int i = 0; i < 4; ++i)
            a[i] = *(const bf16x8*)&As[(wm + i*16 + l16)*128 + sw];
        #pragma unroll
        for (int j = 0; j < 4; ++j)
            b[j] = *(const bf16x8*)&Bs[(wn + j*16 + l16)*128 + sw];
        #pragma unroll
        for (int i = 0; i < 4; ++i)
            #pragma unroll
            for (int j = 0; j < 4; ++j)
                acc[i][j] = __builtin_amdgcn_mfma_f32_16x16x32_bf16(a[i], b[j], acc[i][j], 0, 0, 0);
    }

    #pragma unroll
    for (int i = 0; i < 4; ++i) {
        int rowb = m0 + wm + i*16 + quad*4;
        #pragma unroll
        for (int j = 0; j < 4; ++j) {
            int col = n0 + wn + j*16 + l16;
            float* p = out0 + (size_t)rowb * SIMW + col;
            #pragma unroll
            for (int r = 0; r < 4; ++r) p[(size_t)r * SIMW] = acc[i][j][r];
        }
    }
}

// ---- noise_similarity (exact fp32): out1[b*5+nn][c*512+j] ----
__global__ void noise_sim_k(const float* __restrict__ feat, const float* __restrict__ mem,
                            float* __restrict__ out1) {
    __shared__ float nv[20*128];
    int t = threadIdx.x;
    for (int idx = t; idx < 2560; idx += 256) {
        int r = idx >> 7, v = idx & 127;
        int b = r / 5, nn = r - b*5;
        nv[idx] = feat[(size_t)(b*517 + 512 + nn)*128 + v];
    }
    __syncthreads();
    int col = blockIdx.x * 256 + t;           // 0..32767
    int c = col >> 9, j = col & 511;
    const float* mc = mem + c*65536 + j;
    float acc[20];
    #pragma unroll
    for (int r = 0; r < 20; ++r) acc[r] = 0.f;
    for (int v = 0; v < 128; ++v) {
        float m = mc[(size_t)v*512];
        #pragma unroll
        for (int r = 0; r < 20; ++r) acc[r] += nv[r*128 + v] * m;
    }
    #pragma unroll
    for (int r = 0; r < 20; ++r) out1[(size_t)r*CJ + col] = acc[r];
}

// ---- new_memory (exact fp32, two-pass recompute) ----
__global__ void mem_update(const float* __restrict__ feat, const void* __restrict__ visible,
                           const int* __restrict__ label, const float* __restrict__ mem,
                           float* __restrict__ out2) {
    int t = threadIdx.x;
    int c = blockIdx.x >> 1;
    int j = (blockIdx.x & 1) * 256 + t;

    // detect visible storage width: int8 (jax bool) vs int32
    __shared__ int s_u8;
    if (t == 0) {
        const unsigned* vi = (const unsigned*)visible;
        int u8 = 0;
        for (int w = 0; w < 512; ++w) if (vi[w] > 1u) { u8 = 1; break; }
        s_u8 = u8;
    }
    __syncthreads();

    int labs[4]; int cnt = 0;
    #pragma unroll
    for (int b = 0; b < 4; ++b) { labs[b] = label[b]; cnt += (labs[b] == c); }
    float coef[4];
    #pragma unroll
    for (int b = 0; b < 4; ++b) {
        bool vis;
        if (s_u8) vis = ((const unsigned char*)visible)[b*512 + j] != 0;
        else      vis = ((const int*)visible)[b*512 + j] != 0;
        coef[b] = (labs[b] == c && vis && cnt > 0) ? 0.1f / (float)cnt : 0.0f;
    }
    const float* mcol = mem + c*65536 + j;

    float sumsq = 0.f;
    if (cnt == 0) {                 // uniform branch per block
        for (int v = 0; v < 128; ++v) { float m = mcol[v*512]; sumsq += m*m; }
        float inv = 1.0f / fmaxf(sqrtf(sumsq), 1e-12f);
        for (int v = 0; v < 128; ++v) out2[c*65536 + v*512 + j] = mcol[v*512] * inv;
    } else {
        for (int v = 0; v < 128; ++v) {
            float tv = 0.9f * mcol[v*512];
            #pragma unroll
            for (int b = 0; b < 4; ++b) tv += coef[b] * feat[(size_t)(b*517 + j)*128 + v];
            sumsq += tv*tv;
        }
        float inv = 1.0f / fmaxf(sqrtf(sumsq), 1e-12f);
        for (int v = 0; v < 128; ++v) {
            float tv = 0.9f * mcol[v*512];
            #pragma unroll
            for (int b = 0; b < 4; ++b) tv += coef[b] * feat[(size_t)(b*517 + j)*128 + v];
            out2[c*65536 + v*512 + j] = tv * inv;
        }
    }
}

// ---- new_clutter_bank ----
__global__ void clutter_k(const float* __restrict__ feat, const float* __restrict__ clut,
                          const int* __restrict__ lru, float* __restrict__ out3) {
    int n = blockIdx.x * 256 + threadIdx.x;   // 0..20479
    int off = ((lru[0] + 1) % (BANK / BQ)) * (NCLUT * BQ);
    int k = n - off;
    bool repl = (k >= 0 && k < NCLUT*BQ);
    const float* src; int stride;
    if (repl) { int b = k / 5, nn = k - b*5; src = feat + (size_t)(b*517 + 512 + nn)*128; stride = 1; }
    else      { src = clut + n; stride = NB; }
    float ss = 0.f;
    for (int v = 0; v < 128; ++v) { float x = src[(size_t)v*stride]; ss += x*x; }
    float inv = 1.0f / fmaxf(sqrtf(ss), 1e-12f);
    for (int v = 0; v < 128; ++v) out3[(size_t)v*NB + n] = src[(size_t)v*stride] * inv;
}

extern "C" void kernel_launch(void* const* d_in, const int* in_sizes, int n_in,
                              void* d_out, int out_size, void* d_ws, size_t ws_size,
                              hipStream_t stream) {
    const float* feat = (const float*)d_in[0];
    const void*  vis  = d_in[1];
    const int*   lab  = (const int*)d_in[2];
    const float* mem  = (const float*)d_in[3];
    const float* clut = (const float*)d_in[4];
    const int*   lru  = (const int*)d_in[5];
    float* out  = (float*)d_out;
    float* out0 = out + OUT0_OFF;
    float* out1 = out + OUT1_OFF;
    float* out2 = out + OUT2_OFF;
    float* out3 = out + OUT3_OFF;

    // Scratch in d_out tail (out1+out2 region, consumed by GEMM before overwritten):
    unsigned short* BT  = (unsigned short*)(out + OUT1_OFF);   // 53248*128 bf16 = 13.6 MB
    unsigned short* Abf = BT + (size_t)SIMW * 128;             // 2048*128 bf16 = 0.5 MB

    hipLaunchKernelGGL(prep_a,      dim3(1024),    dim3(256), 0, stream, feat, Abf);
    hipLaunchKernelGGL(prep_bt,     dim3(832),     dim3(256), 0, stream, mem, clut, BT);
    hipLaunchKernelGGL(gemm_sim,    dim3(416, 16), dim3(256), 0, stream, Abf, BT, out0);
    hipLaunchKernelGGL(noise_sim_k, dim3(128),     dim3(256), 0, stream, feat, mem, out1);
    hipLaunchKernelGGL(mem_update,  dim3(128),     dim3(256), 0, stream, feat, vis, lab, mem, out2);
    hipLaunchKernelGGL(clutter_k,   dim3(80),      dim3(256), 0, stream, feat, clut, lru, out3);
}